// Round 5
// baseline (12206.728 us; speedup 1.0000x reference)
//
#include <hip/hip_runtime.h>
#include <math.h>

// ---------------------------------------------------------------------------
// Seq2SeqLSTM on MI355X -- Round 5: event-flag pipelined chain.
//
// Round-4 evidence: fence removal = no change -> 17us/phase is structural:
// monolithic barrier full-stop + ds_read_b32-dominated partials + serialized
// act sections. Redesign:
//  * flag0[q]/flag1[q] event counters (1 agent add per WG via LDS gather);
//    phase q polls flag0[q-1], flag1[q-2] only. flag0[q-1]==64 transitively
//    proves all WGs finished phase q-1 staging -> slab parity reuse safe.
//  * act0 on waves 0-3, act1 on waves 4-7 (parallel, disjoint SIMDs);
//    3 syncthreads per phase, no trailing barrier.
//  * paired slab layout: publish h[j] at pair-pos ((j>>1)*128+2r+(j&1)) so
//    staging = flat u64 copy and partial loops read float2 via ds_read_b64;
//    float2 ext-vector FMA -> v_pk_fma_f32 (2x fp32 rate); float2 scalar
//    weight loads. act-owned k-quarter partials stay in regs (pL0/pL1 = 12
//    slots; LDS 152 KB).
// ---------------------------------------------------------------------------

#define B     64
#define SLEN  64
#define TLEN  32
#define HID   256
#define EMBD  256
#define G4    1024
#define VOC   32000
#define NPRED 31
#define NWG   64

typedef float v2f __attribute__((ext_vector_type(2)));
typedef unsigned long long u64;

__device__ __forceinline__ float sigf(float x){ return 1.0f/(1.0f+__expf(-x)); }

__device__ __forceinline__ void gstoref(float* p, float v){
  __hip_atomic_store(p, v, __ATOMIC_RELAXED, __HIP_MEMORY_SCOPE_AGENT);
}
__device__ __forceinline__ u64 gload64(const u64* p){
  return __hip_atomic_load(p, __ATOMIC_RELAXED, __HIP_MEMORY_SCOPE_AGENT);
}
__device__ __forceinline__ int gload32(const int* p){
  return __hip_atomic_load(p, __ATOMIC_RELAXED, __HIP_MEMORY_SCOPE_AGENT);
}

// --------------------------------- init ------------------------------------
__global__ void k_init(const int* __restrict__ tgt, int* __restrict__ buf){
  int r = threadIdx.x;
  if (r < B) buf[r*TLEN] = tgt[r*TLEN];
}

__global__ void k_zero(int* __restrict__ ctr){
  ctr[blockIdx.x*1024 + threadIdx.x] = 0;
}

// --------------------------------- xproj -----------------------------------
// out[(pos*G4 + j)*64 + r] = b0[j] + sum_k emb[tok[r]][k] * W[j][k]
__global__ __launch_bounds__(256) void k_xproj(
    const int* __restrict__ tok, int tok_stride, int pos0,
    const float* __restrict__ emb, const float* __restrict__ W,
    const float* __restrict__ b0, float* __restrict__ out)
{
  __shared__ float xT[128][64];
  const int tid  = threadIdx.x;
  const int lane = tid & 63;
  const int wv   = __builtin_amdgcn_readfirstlane(tid >> 6);
  const int pos  = pos0 + blockIdx.y;
  const int jbase= blockIdx.x*32 + wv*8;

  const int rS = tid >> 2, klane = tid & 3;
  const int tokrow = tok[rS*tok_stride + pos];
  const float* xsrc = emb + (size_t)tokrow*EMBD;

  float acc[8];
  #pragma unroll
  for (int jj=0;jj<8;jj++) acc[jj]=0.f;

  for (int c=0;c<2;c++){
    __syncthreads();
    #pragma unroll
    for (int i=0;i<32;i++){
      int k = klane + 4*i;
      xT[k][rS] = xsrc[c*128 + k];
    }
    __syncthreads();
    for (int kc=0;kc<8;kc++){
      float x[16];
      #pragma unroll
      for (int i=0;i<16;i++) x[i] = xT[kc*16+i][lane];
      #pragma unroll
      for (int jj=0;jj<8;jj++){
        const float* Wp = W + (size_t)(jbase+jj)*EMBD + c*128 + kc*16;
        float s = 0.f;
        #pragma unroll
        for (int i=0;i<16;i++) s += Wp[i]*x[i];
        acc[jj] += s;
      }
    }
  }
  #pragma unroll
  for (int jj=0;jj<8;jj++){
    int j = jbase+jj;
    out[((size_t)pos*G4 + j)*64 + lane] = acc[jj] + b0[j];
  }
}

// --------------------------------- chain -----------------------------------
// Slabs h0T/h1T: [2 parities][16384 floats], PAIRED layout: value for h-index
// j, row r lives at (j>>1)*128 + 2r + (j&1)  == u64 pair (j,j+1) per row.
// h0P/h1P/c0P/c1P: plain [k][r] persistent state across dispatches.
__global__ __launch_bounds__(1024) void k_chain5(
    const float* __restrict__ xp, int nsteps,
    const float* __restrict__ Whh0, const float* __restrict__ Wih1,
    const float* __restrict__ Whh1, const float* __restrict__ b1,
    float* __restrict__ h0P, float* __restrict__ h1P,
    float* __restrict__ c0P, float* __restrict__ c1P,
    float* __restrict__ h0T, float* __restrict__ h1T,
    int* __restrict__ flag0, int* __restrict__ flag1, int initzero)
{
  __shared__ __align__(16) float h0s[16384];     // 64 KB, paired layout
  __shared__ __align__(16) float h1s[16384];     // 64 KB, paired layout
  __shared__ float pL0[12][4][64];               // 12 KB (kq>=1 partials)
  __shared__ float pL1[12][4][64];               // 12 KB (kq!=1 partials)
  __shared__ int a0c[2], a1c[2];

  const int tid  = threadIdx.x;
  const int lane = tid & 63;
  const int wv   = __builtin_amdgcn_readfirstlane(tid >> 6);
  const int jsub = wv & 3, kq = wv >> 2;
  const int bid  = blockIdx.x;
  const int j    = bid*4 + jsub;
  const int k0   = kq << 6;

  // wave-uniform weight row slices as float2 (k0 even -> 8B aligned)
  const v2f* Wr0 = (const v2f*)(Whh0 + (size_t)(0*HID+j)*HID + k0);
  const v2f* Wr1 = (const v2f*)(Whh0 + (size_t)(1*HID+j)*HID + k0);
  const v2f* Wr2 = (const v2f*)(Whh0 + (size_t)(2*HID+j)*HID + k0);
  const v2f* Wr3 = (const v2f*)(Whh0 + (size_t)(3*HID+j)*HID + k0);
  const v2f* Wi0 = (const v2f*)(Wih1 + (size_t)(0*HID+j)*HID + k0);
  const v2f* Wi1 = (const v2f*)(Wih1 + (size_t)(1*HID+j)*HID + k0);
  const v2f* Wi2 = (const v2f*)(Wih1 + (size_t)(2*HID+j)*HID + k0);
  const v2f* Wi3 = (const v2f*)(Wih1 + (size_t)(3*HID+j)*HID + k0);
  const v2f* Wh0 = (const v2f*)(Whh1 + (size_t)(0*HID+j)*HID + k0);
  const v2f* Wh1 = (const v2f*)(Whh1 + (size_t)(1*HID+j)*HID + k0);
  const v2f* Wh2 = (const v2f*)(Whh1 + (size_t)(2*HID+j)*HID + k0);
  const v2f* Wh3 = (const v2f*)(Whh1 + (size_t)(3*HID+j)*HID + k0);

  float c0 = 0.f, c1 = 0.f;
  float bb0 = 0.f, bb1 = 0.f, bb2 = 0.f, bb3 = 0.f;
  if (wv < 4 && !initzero)              c0 = c0P[j*64 + lane];
  if (wv >= 4 && wv < 8){
    bb0 = b1[0*HID+j]; bb1 = b1[1*HID+j];
    bb2 = b1[2*HID+j]; bb3 = b1[3*HID+j];
    if (!initzero)                      c1 = c1P[j*64 + lane];
  }

  for (int q = 0; q <= nsteps; ++q){
    // ---- A: poll event flags (single poller), then sync
    if (tid == 0){
      int g = 0;
      if (q >= 1) while (gload32(flag0 + q - 1) < NWG && ++g < (1<<24)) {}
      g = 0;
      if (q >= 2) while (gload32(flag1 + q - 2) < NWG && ++g < (1<<24)) {}
    }
    __syncthreads();   // A
    if (tid == 8*64){ a0c[q&1] = 0; a1c[(q+1)&1] = 0; }

    // act0 xp prefetch (cached loads, consumed after sync C)
    float xv0=0.f, xv1=0.f, xv2=0.f, xv3=0.f;
    if (wv < 4 && q < nsteps){
      const float* xq = xp + ((size_t)q*G4)*64 + lane;
      xv0 = xq[(0*HID+j)*64]; xv1 = xq[(1*HID+j)*64];
      xv2 = xq[(2*HID+j)*64]; xv3 = xq[(3*HID+j)*64];
    }

    // ---- stage h0s <- h0(q-1), h1s <- h1(q-2)
    if (q == 0){
      if (initzero){
        u64* d = (u64*)h0s;
        #pragma unroll
        for (int i=0;i<8;i++) d[tid + i*1024] = 0ull;
      } else {
        #pragma unroll
        for (int i=0;i<8;i++){
          int p = tid + i*1024, kp = p >> 6, r = p & 63;
          v2f v; v.x = h0P[(2*kp)*64 + r]; v.y = h0P[(2*kp+1)*64 + r];
          ((v2f*)h0s)[p] = v;
        }
      }
    } else {
      const u64* s = (const u64*)(h0T + (size_t)((q-1)&1)*16384);
      u64* d = (u64*)h0s;
      #pragma unroll
      for (int i=0;i<8;i++) d[tid + i*1024] = gload64(s + tid + i*1024);
    }
    if (q <= 1){
      if (initzero){
        u64* d = (u64*)h1s;
        #pragma unroll
        for (int i=0;i<8;i++) d[tid + i*1024] = 0ull;
      } else {
        #pragma unroll
        for (int i=0;i<8;i++){
          int p = tid + i*1024, kp = p >> 6, r = p & 63;
          v2f v; v.x = h1P[(2*kp)*64 + r]; v.y = h1P[(2*kp+1)*64 + r];
          ((v2f*)h1s)[p] = v;
        }
      }
    } else {
      const u64* s = (const u64*)(h1T + (size_t)(q&1)*16384);
      u64* d = (u64*)h1s;
      #pragma unroll
      for (int i=0;i<8;i++) d[tid + i*1024] = gload64(s + tid + i*1024);
    }
    __syncthreads();   // B

    // ---- L0 partials for step q (float2 pk-fma)
    v2f A0={0.f,0.f}, A1={0.f,0.f}, A2={0.f,0.f}, A3={0.f,0.f};
    if (q < nsteps){
      const v2f* hp = ((const v2f*)h0s) + kq*2048 + lane;
      #pragma unroll 8
      for (int kk=0; kk<32; ++kk){
        v2f h = hp[kk*64];
        A0 += Wr0[kk]*h; A1 += Wr1[kk]*h; A2 += Wr2[kk]*h; A3 += Wr3[kk]*h;
      }
      if (kq >= 1){
        int s = (kq-1)*4 + jsub;
        pL0[s][0][lane]=A0.x+A0.y; pL0[s][1][lane]=A1.x+A1.y;
        pL0[s][2][lane]=A2.x+A2.y; pL0[s][3][lane]=A3.x+A3.y;
      }
    }

    // ---- L1 partials for step q-1
    v2f B0={0.f,0.f}, B1={0.f,0.f}, B2={0.f,0.f}, B3={0.f,0.f};
    if (q >= 1){
      const v2f* ha = ((const v2f*)h0s) + kq*2048 + lane;
      const v2f* hb = ((const v2f*)h1s) + kq*2048 + lane;
      #pragma unroll 4
      for (int kk=0; kk<32; ++kk){
        v2f x = ha[kk*64], y = hb[kk*64];
        B0 += Wi0[kk]*x + Wh0[kk]*y;
        B1 += Wi1[kk]*x + Wh1[kk]*y;
        B2 += Wi2[kk]*x + Wh2[kk]*y;
        B3 += Wi3[kk]*x + Wh3[kk]*y;
      }
      if (kq != 1){
        int s = ((kq==0) ? 0 : (kq-1))*4 + jsub;
        pL1[s][0][lane]=B0.x+B0.y; pL1[s][1][lane]=B1.x+B1.y;
        pL1[s][2][lane]=B2.x+B2.y; pL1[s][3][lane]=B3.x+B3.y;
      }
    }
    __syncthreads();   // C

    // ---- act0 (waves 0-3): reduce + activate + publish h0(q)
    if (wv < 4 && q < nsteps){
      float g0 = A0.x+A0.y + xv0, g1 = A1.x+A1.y + xv1;
      float g2 = A2.x+A2.y + xv2, g3 = A3.x+A3.y + xv3;
      #pragma unroll
      for (int i=0;i<3;i++){
        g0 += pL0[i*4+jsub][0][lane]; g1 += pL0[i*4+jsub][1][lane];
        g2 += pL0[i*4+jsub][2][lane]; g3 += pL0[i*4+jsub][3][lane];
      }
      c0 = sigf(g1)*c0 + sigf(g0)*tanhf(g2);
      float h = sigf(g3)*tanhf(c0);
      float* dst = h0T + (size_t)(q&1)*16384;
      gstoref(dst + (j>>1)*128 + 2*lane + (j&1), h);
      if (q == nsteps-1) h0P[j*64 + lane] = h;
      asm volatile("s_waitcnt vmcnt(0)" ::: "memory");
      if (lane == 0){
        int old = atomicAdd(&a0c[q&1], 1);
        if (old == 3)
          __hip_atomic_fetch_add(flag0 + q, 1, __ATOMIC_RELAXED,
                                 __HIP_MEMORY_SCOPE_AGENT);
      }
    }

    // ---- act1 (waves 4-7): reduce + activate + publish h1(q-1)
    if (wv >= 4 && wv < 8 && q >= 1){
      float g0 = B0.x+B0.y + bb0, g1 = B1.x+B1.y + bb1;
      float g2 = B2.x+B2.y + bb2, g3 = B3.x+B3.y + bb3;
      #pragma unroll
      for (int i=0;i<3;i++){
        g0 += pL1[i*4+jsub][0][lane]; g1 += pL1[i*4+jsub][1][lane];
        g2 += pL1[i*4+jsub][2][lane]; g3 += pL1[i*4+jsub][3][lane];
      }
      c1 = sigf(g1)*c1 + sigf(g0)*tanhf(g2);
      float h = sigf(g3)*tanhf(c1);
      float* dst = h1T + (size_t)((q-1)&1)*16384;
      gstoref(dst + (j>>1)*128 + 2*lane + (j&1), h);
      if (q == nsteps) h1P[j*64 + lane] = h;
      asm volatile("s_waitcnt vmcnt(0)" ::: "memory");
      if (lane == 0){
        int old = atomicAdd(&a1c[(q-1)&1], 1);
        if (old == 3)
          __hip_atomic_fetch_add(flag1 + q - 1, 1, __ATOMIC_RELAXED,
                                 __HIP_MEMORY_SCOPE_AGENT);
      }
    }
    // no trailing barrier: next-phase sync A orders LDS reuse.
  }

  if (wv < 4)               c0P[j*64 + lane] = c0;
  if (wv >= 4 && wv < 8)    c1P[j*64 + lane] = c1;
}

// --------------------------------- pred ------------------------------------
__global__ __launch_bounds__(256) void k_pred(
    const float* __restrict__ h1, const float* __restrict__ Wout,
    const float* __restrict__ bout, float* __restrict__ dout, int t,
    float* __restrict__ pval, int* __restrict__ pidx)
{
  __shared__ float xT[128][64];
  __shared__ float cval[4][64];
  __shared__ int   cidx[4][64];
  const int tid  = threadIdx.x;
  const int lane = tid & 63;
  const int wv   = __builtin_amdgcn_readfirstlane(tid >> 6);
  const int vbase= blockIdx.x*32 + wv*8;

  float acc[8];
  #pragma unroll
  for (int vv=0;vv<8;vv++) acc[vv]=0.f;

  for (int c=0;c<2;c++){
    __syncthreads();
    {
      const float4* s4 = (const float4*)(h1 + c*8192);
      float4* d4 = (float4*)&xT[0][0];
      #pragma unroll
      for (int i=0;i<8;i++) d4[tid + i*256] = s4[tid + i*256];
    }
    __syncthreads();
    for (int kc=0;kc<8;kc++){
      float x[16];
      #pragma unroll
      for (int i=0;i<16;i++) x[i] = xT[kc*16+i][lane];
      #pragma unroll
      for (int vv=0;vv<8;vv++){
        const float* Wp = Wout + (size_t)(vbase+vv)*HID + c*128 + kc*16;
        float s = 0.f;
        #pragma unroll
        for (int i=0;i<16;i++) s += Wp[i]*x[i];
        acc[vv] += s;
      }
    }
  }

  const int r = lane;
  float best = -INFINITY; int bi = 0;
  #pragma unroll
  for (int vv=0; vv<8; vv++){
    int v = vbase + vv;
    float val = acc[vv] + bout[v];
    dout[((size_t)r*NPRED + t)*VOC + v] = val;
    if (val > best){ best = val; bi = v; }
  }
  cval[wv][lane] = best; cidx[wv][lane] = bi;
  __syncthreads();
  if (tid < 64){
    float bb = cval[0][tid]; int bbi = cidx[0][tid];
    #pragma unroll
    for (int w=1; w<4; w++){
      float v = cval[w][tid];
      if (v > bb){ bb = v; bbi = cidx[w][tid]; }
    }
    pval[(size_t)tid*1024 + blockIdx.x] = bb;
    pidx[(size_t)tid*1024 + blockIdx.x] = bbi;
  }
}

// ------------------------------ argmax final --------------------------------
__global__ __launch_bounds__(256) void k_amax(
    const float* __restrict__ pval, const int* __restrict__ pidx,
    int* __restrict__ buf, int t)
{
  __shared__ float sv[256]; __shared__ int si[256];
  const int r = blockIdx.x, tid = threadIdx.x;
  float best = -INFINITY; int bi = 0x7fffffff;
  for (int w = tid; w < 1000; w += 256){
    float v = pval[(size_t)r*1024 + w]; int ii = pidx[(size_t)r*1024 + w];
    if (v > best || (v == best && ii < bi)){ best = v; bi = ii; }
  }
  sv[tid] = best; si[tid] = bi;
  __syncthreads();
  for (int s2 = 128; s2 > 0; s2 >>= 1){
    if (tid < s2){
      float v = sv[tid+s2]; int ii = si[tid+s2];
      if (v > sv[tid] || (v == sv[tid] && ii < si[tid])){ sv[tid]=v; si[tid]=ii; }
    }
    __syncthreads();
  }
  if (tid == 0) buf[r*TLEN + t + 1] = si[0];
}

// -------------------------------- launch ------------------------------------
extern "C" void kernel_launch(void* const* d_in, const int* in_sizes, int n_in,
                              void* d_out, int out_size, void* d_ws, size_t ws_size,
                              hipStream_t stream)
{
  const int*   input_seq  = (const int*)d_in[0];
  const int*   target_seq = (const int*)d_in[1];
  const float* enc_emb = (const float*)d_in[2];
  const float* dec_emb = (const float*)d_in[3];
  const float* enc_Wih = (const float*)d_in[4];
  const float* enc_Whh = (const float*)d_in[5];
  const float* enc_b   = (const float*)d_in[6];
  const float* dec_Wih = (const float*)d_in[7];
  const float* dec_Whh = (const float*)d_in[8];
  const float* dec_b   = (const float*)d_in[9];
  const float* W_out   = (const float*)d_in[10];
  const float* b_out   = (const float*)d_in[11];
  float* out = (float*)d_out;

  float* ws   = (float*)d_ws;
  float* xp_e = ws;                               // 64*1024*64
  float* xp_d = xp_e + (size_t)SLEN*G4*64;        // 32*1024*64
  float* h0P  = xp_d + (size_t)TLEN*G4*64;        // 256*64
  float* h1P  = h0P + HID*64;
  float* c0P  = h1P + HID*64;
  float* c1P  = c0P + HID*64;
  float* h0T  = c1P + HID*64;                     // 2*16384 (paired slabs)
  float* h1T  = h0T + 2*HID*64;
  float* pval = h1T + 2*HID*64;                   // 64*1024
  int*   pidx = (int*)(pval + (size_t)B*1024);    // 64*1024
  int*   buf  = pidx + (size_t)B*1024;            // 64*32
  int*   flag0= buf + B*TLEN;                     // 2048
  int*   flag1= flag0 + 2048;                     // 2048

  k_init<<<1, 64, 0, stream>>>(target_seq, buf);
  k_zero<<<4, 1024, 0, stream>>>(flag0);          // zeros flag0+flag1

  // encoder
  k_xproj<<<dim3(32, SLEN), 256, 0, stream>>>(input_seq, SLEN, 0, enc_emb,
        enc_Wih, enc_b, xp_e);
  k_chain5<<<NWG, 1024, 0, stream>>>(xp_e, SLEN,
        enc_Whh, enc_Wih + (size_t)G4*EMBD, enc_Whh + (size_t)G4*HID,
        enc_b + G4, h0P, h1P, c0P, c1P, h0T, h1T, flag0, flag1, 1);

  // decoder greedy loop (outer step t replays positions 0..t)
  int off = SLEN + 1;
  for (int t = 0; t < NPRED; t++){
    k_xproj<<<dim3(32, 1), 256, 0, stream>>>(buf, TLEN, t, dec_emb,
        dec_Wih, dec_b, xp_d);
    k_chain5<<<NWG, 1024, 0, stream>>>(xp_d, t+1,
        dec_Whh, dec_Wih + (size_t)G4*EMBD, dec_Whh + (size_t)G4*HID,
        dec_b + G4, h0P, h1P, c0P, c1P, h0T, h1T, flag0 + off, flag1 + off, 0);
    off += t + 2;
    k_pred<<<1000, 256, 0, stream>>>(h1P, W_out, b_out, out, t, pval, pidx);
    k_amax<<<B, 256, 0, stream>>>(pval, pidx, buf, t);
  }
}